// Round 4
// baseline (1305.187 us; speedup 1.0000x reference)
//
#include <hip/hip_runtime.h>

// ---------------------------------------------------------------------------
// GPT-J attention on MI355X (gfx950), bf16 MFMA pipeline.
// B=2 S=2048 E=4096 H=16 D=256 ROT=64
// R4: gemm_qkv split into 3 gemm_proj dispatches (profile visibility +
//     streamed weights); attn gets XCD-local grid mapping (all blocks of a
//     (b,h) land on one XCD -> K/V stay in that XCD's L2).
// ---------------------------------------------------------------------------

typedef __bf16 bf16;
typedef bf16  bf16x4 __attribute__((ext_vector_type(4)));
typedef bf16  bf16x8 __attribute__((ext_vector_type(8)));
typedef float f32x4  __attribute__((ext_vector_type(4)));

#define SEQ 2048
#define ED  4096
#define NH  16
#define HD  256

__device__ __forceinline__ void async_load16(const void* g, void* l) {
  __builtin_amdgcn_global_load_lds(
      (const __attribute__((address_space(1))) void*)g,
      (__attribute__((address_space(3))) void*)l, 16, 0, 0);
}

// ---------------------------------------------------------------------------
// fused fp32 -> bf16 conversion, 4 sources, 4 elems/thread
// ---------------------------------------------------------------------------
__global__ void cvt4_f32_bf16(const float* __restrict__ s0,
                              const float* __restrict__ s1,
                              const float* __restrict__ s2,
                              const float* __restrict__ s3,
                              bf16* __restrict__ d0, bf16* __restrict__ d1,
                              bf16* __restrict__ d2, bf16* __restrict__ d3) {
  int sec = blockIdx.x >> 14;              // 16384 blocks / section
  int idx = ((blockIdx.x & 16383) * 256 + threadIdx.x) * 4;
  const float* s = sec == 0 ? s0 : sec == 1 ? s1 : sec == 2 ? s2 : s3;
  bf16* d = sec == 0 ? d0 : sec == 1 ? d1 : sec == 2 ? d2 : d3;
  float4 v = *(const float4*)(s + idx);
  bf16x4 o;
  o.x = (bf16)v.x; o.y = (bf16)v.y; o.z = (bf16)v.z; o.w = (bf16)v.w;
  *(bf16x4*)(d + idx) = o;
}

__global__ void cvt_f32_bf16(const float* __restrict__ src,
                             bf16* __restrict__ dst, int n) {
  int idx = (blockIdx.x * 256 + threadIdx.x) * 4;
  if (idx < n) {
    float4 v = *(const float4*)(src + idx);
    bf16x4 o;
    o.x = (bf16)v.x; o.y = (bf16)v.y; o.z = (bf16)v.z; o.w = (bf16)v.w;
    *(bf16x4*)(dst + idx) = o;
  }
}

// ---------------------------------------------------------------------------
// bt-GEMM: Ob = A @ W^T, A: 4096x4096 bf16, W: 4096x4096 bf16 (one tensor).
// 128x128 tile, 4 waves, BK=32, global_load_lds staging (16B).
// Epilogue: coalesced store to (b,h,s,d).
// ---------------------------------------------------------------------------
__global__ __launch_bounds__(256) void gemm_proj(
    const bf16* __restrict__ A, const bf16* __restrict__ W,
    bf16* __restrict__ Ob) {
  __shared__ bf16 As[128 * 32];
  __shared__ bf16 Bs[128 * 32];
  const int tid = threadIdx.x;
  const int w = tid >> 6, lane = tid & 63;
  const int wm = w >> 1, wn = w & 1;
  const int lo = lane & 15, hi = lane >> 4;

  // band swizzle: 8 n-tiles per band
  const int flat = blockIdx.y * 32 + blockIdx.x;  // 0..1023
  const int band = flat >> 8;                     // 0..3
  const int xm = (flat & 255) >> 3;               // 0..31
  const int xn = (band << 3) | (flat & 7);        // 0..31
  const int tm = xm * 128;
  const int tn = xn * 128;

  const int rA0 = lane >> 2;
  const int cA0 = (lane & 3) * 8;

  const bf16* Ab = A + (size_t)tm * ED;
  const bf16* Wb = W + (size_t)tn * ED;

  f32x4 acc[4][4] = {};

  for (int k0 = 0; k0 < ED; k0 += 32) {
#pragma unroll
    for (int i = 0; i < 2; ++i) {
      int ci = w * 2 + i;
      int r = ci * 16 + rA0;
      async_load16(Ab + (size_t)r * ED + k0 + cA0, &As[ci * 512]);
      async_load16(Wb + (size_t)r * ED + k0 + cA0, &Bs[ci * 512]);
    }
    __syncthreads();
    bf16x8 af[4], bfr[4];
#pragma unroll
    for (int mt = 0; mt < 4; ++mt)
      af[mt] = *(const bf16x8*)&As[(wm * 64 + mt * 16 + lo) * 32 + hi * 8];
#pragma unroll
    for (int nt = 0; nt < 4; ++nt)
      bfr[nt] = *(const bf16x8*)&Bs[(wn * 64 + nt * 16 + lo) * 32 + hi * 8];
#pragma unroll
    for (int mt = 0; mt < 4; ++mt)
#pragma unroll
      for (int nt = 0; nt < 4; ++nt)
        acc[mt][nt] = __builtin_amdgcn_mfma_f32_16x16x32_bf16(
            af[mt], bfr[nt], acc[mt][nt], 0, 0, 0);
    __syncthreads();
  }

#pragma unroll
  for (int mt = 0; mt < 4; ++mt) {
#pragma unroll
    for (int nt = 0; nt < 4; ++nt) {
#pragma unroll
      for (int r = 0; r < 4; ++r) {
        int m = tm + wm * 64 + mt * 16 + hi * 4 + r;
        int f = tn + wn * 64 + nt * 16 + lo;
        int b = m >> 11, s = m & 2047;
        int h = f >> 8, d = f & 255;
        Ob[(((size_t)(b * NH + h) * SEQ) + s) * HD + d] = (bf16)acc[mt][nt][r];
      }
    }
  }
}

// ---------------------------------------------------------------------------
// V transpose: (b,h,s,d) -> (b,h,d,s). 64x64 tiles via padded LDS.
// ---------------------------------------------------------------------------
__global__ __launch_bounds__(256) void transpose_v(const bf16* __restrict__ src,
                                                   bf16* __restrict__ dst) {
  __shared__ bf16 T[64][72];
  const int bh = blockIdx.z;
  const int st = blockIdx.x;
  const int dt = blockIdx.y;
  const bf16* S = src + ((size_t)bh * SEQ + st * 64) * HD + dt * 64;
#pragma unroll
  for (int p = 0; p < 2; ++p) {
    int r = p * 32 + (threadIdx.x >> 3), c = (threadIdx.x & 7) * 8;
    *(bf16x8*)&T[r][c] = *(const bf16x8*)(S + (size_t)r * HD + c);
  }
  __syncthreads();
  bf16* D = dst + ((size_t)bh * HD + dt * 64) * SEQ + st * 64;
#pragma unroll
  for (int p = 0; p < 2; ++p) {
    int r = p * 32 + (threadIdx.x >> 3), c = (threadIdx.x & 7) * 8;
    bf16x8 v;
#pragma unroll
    for (int j = 0; j < 8; ++j) v[j] = T[c + j][r];
    *(bf16x8*)(D + (size_t)r * SEQ + c) = v;
  }
}

// ---------------------------------------------------------------------------
// out-proj GEMM, fp32 epilogue to d_out (row-major 4096x4096)
// ---------------------------------------------------------------------------
__global__ __launch_bounds__(256) void gemm_out(
    const bf16* __restrict__ A, const bf16* __restrict__ W,
    float* __restrict__ C) {
  __shared__ bf16 As[128 * 32];
  __shared__ bf16 Bs[128 * 32];
  const int tid = threadIdx.x;
  const int w = tid >> 6, lane = tid & 63;
  const int wm = w >> 1, wn = w & 1;
  const int lo = lane & 15, hi = lane >> 4;
  const int tm = blockIdx.x * 128;
  const int tn = blockIdx.y * 128;

  const int rA0 = lane >> 2;
  const int cA0 = (lane & 3) * 8;

  const bf16* Ab = A + (size_t)tm * ED;
  const bf16* Wb = W + (size_t)tn * ED;

  f32x4 acc[4][4] = {};

  for (int k0 = 0; k0 < ED; k0 += 32) {
#pragma unroll
    for (int i = 0; i < 2; ++i) {
      int ci = w * 2 + i;
      int r = ci * 16 + rA0;
      async_load16(Ab + (size_t)r * ED + k0 + cA0, &As[ci * 512]);
      async_load16(Wb + (size_t)r * ED + k0 + cA0, &Bs[ci * 512]);
    }
    __syncthreads();
    bf16x8 af[4], bfr[4];
#pragma unroll
    for (int mt = 0; mt < 4; ++mt)
      af[mt] = *(const bf16x8*)&As[(wm * 64 + mt * 16 + lo) * 32 + hi * 8];
#pragma unroll
    for (int nt = 0; nt < 4; ++nt)
      bfr[nt] = *(const bf16x8*)&Bs[(wn * 64 + nt * 16 + lo) * 32 + hi * 8];
#pragma unroll
    for (int mt = 0; mt < 4; ++mt)
#pragma unroll
      for (int nt = 0; nt < 4; ++nt)
        acc[mt][nt] = __builtin_amdgcn_mfma_f32_16x16x32_bf16(
            af[mt], bfr[nt], acc[mt][nt], 0, 0, 0);
    __syncthreads();
  }

#pragma unroll
  for (int mt = 0; mt < 4; ++mt)
#pragma unroll
    for (int nt = 0; nt < 4; ++nt)
#pragma unroll
      for (int r = 0; r < 4; ++r) {
        int m = tm + wm * 64 + mt * 16 + hi * 4 + r;
        int n = tn + wn * 64 + nt * 16 + lo;
        C[(size_t)m * ED + n] = acc[mt][nt][r];
      }
}

// ---------------------------------------------------------------------------
// RoPE, vectorized: one thread = 4 interleaved pairs (bf16x8, 16 B).
// ---------------------------------------------------------------------------
__global__ void rope_kernel(bf16* __restrict__ Qb, bf16* __restrict__ Kb,
                            const int* __restrict__ pos_ids,
                            const float* __restrict__ emb) {
  int idx = blockIdx.x * 256 + threadIdx.x;
  int g = idx & 7;
  int s = (idx >> 3) & 2047;
  int h = (idx >> 14) & 15;
  int b = (idx >> 18) & 1;
  int t = idx >> 19;
  bf16* T = t ? Kb : Qb;
  int pos = pos_ids[b * SEQ + s];
  const float* e = emb + pos * 64;
  size_t base = (((size_t)(b * NH + h) * SEQ) + s) * HD + g * 8;
  bf16x8 v = *(bf16x8*)(T + base);
  bf16x8 o;
#pragma unroll
  for (int j = 0; j < 4; ++j) {
    int p = g * 4 + j;
    float sn = e[p], cs = e[32 + p];
    float x0 = (float)v[2 * j], x1 = (float)v[2 * j + 1];
    o[2 * j]     = (bf16)(x0 * cs - x1 * sn);
    o[2 * j + 1] = (bf16)(x1 * cs + x0 * sn);
  }
  *(bf16x8*)(T + base) = o;
}

// ---------------------------------------------------------------------------
// Flash attention (causal), qt-paired, XCD-local grid.
// Grid: 512 1-D; flat = slot*32 + bh  =>  flat%8 == bh%8, so all 16 blocks
// of one (b,h) land on the same XCD (round-robin dispatch) and share its L2
// for the 2 MB K+V working set.
// Block processes qt=slot then qt=31-slot -> 33 K-tile iters everywhere.
// XOR-swizzled LDS keeps all b128 reads at free 2-way aliasing.
// ---------------------------------------------------------------------------
__global__ __launch_bounds__(256) void attn_kernel(
    const bf16* __restrict__ Qb, const bf16* __restrict__ Kb,
    const bf16* __restrict__ Vt, bf16* __restrict__ AO) {
  __shared__ bf16 Ks[64 * 256];    // 32 KB
  __shared__ bf16 Vs[256 * 64];    // 32 KB
  __shared__ bf16 Ps[4 * 16 * 64]; // 8 KB, wave-private strips
  const int tid = threadIdx.x;
  const int w = tid >> 6, lane = tid & 63;
  const int lo = lane & 15, hi = lane >> 4;
  const int slot = blockIdx.x >> 5;   // 0..15
  const int bh = blockIdx.x & 31;     // 0..31  (bh%8 = XCD class)

  const bf16* Qh = Qb + (size_t)bh * SEQ * HD;
  const bf16* Kh = Kb + (size_t)bh * SEQ * HD;
  const bf16* Vh = Vt + (size_t)bh * HD * SEQ;
  const int b = bh >> 4, h = bh & 15;

  for (int half = 0; half < 2; ++half) {
    const int qt = half ? (31 - slot) : slot;

    bf16x8 aq[8];
    const int qrow = qt * 64 + w * 16 + lo;
#pragma unroll
    for (int ks = 0; ks < 8; ++ks)
      aq[ks] = *(const bf16x8*)(Qh + (size_t)qrow * HD + ks * 32 + hi * 8);

    f32x4 o[16] = {};
    float mrow[4], lrow[4];
#pragma unroll
    for (int r = 0; r < 4; ++r) { mrow[r] = -3e38f; lrow[r] = 0.f; }

    for (int kt = 0; kt <= qt; ++kt) {
      // stage K tile: 64 rows x 512 B; region ci covers 2 rows.
#pragma unroll
      for (int i = 0; i < 8; ++i) {
        int ci = w * 8 + i;
        int r = ci * 2 + (lane >> 5);
        int cc = (lane & 31) ^ (r & 7);
        async_load16(Kh + ((size_t)(kt * 64 + r)) * HD + cc * 8, &Ks[ci * 512]);
      }
      // stage V tile: 256 d-rows x 128 B; region ci covers 8 rows.
#pragma unroll
      for (int i = 0; i < 8; ++i) {
        int ci = w * 8 + i;
        int d = ci * 8 + (lane >> 3);
        int cc = (lane & 7) ^ (d & 7);
        async_load16(Vh + (size_t)d * SEQ + kt * 64 + cc * 8, &Vs[ci * 512]);
      }
      __syncthreads();

      // S strip: 16 rows x 64 cols
      float sv[4][4];
#pragma unroll
      for (int nt = 0; nt < 4; ++nt) {
        f32x4 sacc = {};
#pragma unroll
        for (int ks = 0; ks < 8; ++ks) {
          int row = nt * 16 + lo;
          bf16x8 bk = *(const bf16x8*)
              &Ks[row * HD + ((((ks << 2) + hi) ^ (row & 7)) << 3)];
          sacc = __builtin_amdgcn_mfma_f32_16x16x32_bf16(aq[ks], bk, sacc, 0, 0, 0);
        }
#pragma unroll
        for (int r = 0; r < 4; ++r) {
          float x = sacc[r] * 0.0625f;
          if (kt == qt) {
            int col = kt * 64 + nt * 16 + lo;
            int row = qt * 64 + w * 16 + hi * 4 + r;
            if (col > row) x = -1e30f;
          }
          sv[nt][r] = x;
        }
      }

      // online softmax (row lives in 16 lanes sharing hi)
      float alpha[4];
#pragma unroll
      for (int r = 0; r < 4; ++r) {
        float mx = fmaxf(fmaxf(sv[0][r], sv[1][r]), fmaxf(sv[2][r], sv[3][r]));
        mx = fmaxf(mx, __shfl_xor(mx, 1));
        mx = fmaxf(mx, __shfl_xor(mx, 2));
        mx = fmaxf(mx, __shfl_xor(mx, 4));
        mx = fmaxf(mx, __shfl_xor(mx, 8));
        float mnew = fmaxf(mrow[r], mx);
        alpha[r] = __expf(mrow[r] - mnew);
        mrow[r] = mnew;
        float sum = 0.f;
#pragma unroll
        for (int nt = 0; nt < 4; ++nt) {
          float p = __expf(sv[nt][r] - mnew);
          sv[nt][r] = p;
          sum += p;
        }
        sum += __shfl_xor(sum, 1);
        sum += __shfl_xor(sum, 2);
        sum += __shfl_xor(sum, 4);
        sum += __shfl_xor(sum, 8);
        lrow[r] = lrow[r] * alpha[r] + sum;
      }

#pragma unroll
      for (int nt2 = 0; nt2 < 16; ++nt2)
#pragma unroll
        for (int r = 0; r < 4; ++r) o[nt2][r] *= alpha[r];

      // P: C-layout -> wave-private swizzled LDS strip -> A-layout
#pragma unroll
      for (int nt = 0; nt < 4; ++nt)
#pragma unroll
        for (int r = 0; r < 4; ++r) {
          int prow = hi * 4 + r;
          int chunk = nt * 2 + (lo >> 3);
          Ps[w * 1024 + prow * 64 + (((chunk ^ (prow & 7)) << 3) | (lo & 7))] =
              (bf16)sv[nt][r];
        }
      bf16x8 pa[2];
#pragma unroll
      for (int k2 = 0; k2 < 2; ++k2)
        pa[k2] = *(const bf16x8*)
            &Ps[w * 1024 + lo * 64 + ((((k2 << 2) + hi) ^ (lo & 7)) << 3)];

      // O += P @ V  (16x64 @ 64x256)
#pragma unroll
      for (int nt2 = 0; nt2 < 16; ++nt2) {
#pragma unroll
        for (int k2 = 0; k2 < 2; ++k2) {
          int row = nt2 * 16 + lo;
          bf16x8 bv = *(const bf16x8*)
              &Vs[row * 64 + ((((k2 << 2) + hi) ^ (row & 7)) << 3)];
          o[nt2] = __builtin_amdgcn_mfma_f32_16x16x32_bf16(pa[k2], bv, o[nt2], 0, 0, 0);
        }
      }
      __syncthreads();
    }

    // epilogue: normalize, write AO as (b, s, h*256+d) bf16
#pragma unroll
    for (int r = 0; r < 4; ++r) {
      float inv = 1.f / lrow[r];
      int srow = qt * 64 + w * 16 + hi * 4 + r;
      size_t base = ((size_t)(b * SEQ + srow)) * ED + h * HD;
#pragma unroll
      for (int nt2 = 0; nt2 < 16; ++nt2)
        AO[base + nt2 * 16 + lo] = (bf16)(o[nt2][r] * inv);
    }
  }
}

// ---------------------------------------------------------------------------
// launch
// ---------------------------------------------------------------------------
extern "C" void kernel_launch(void* const* d_in, const int* in_sizes, int n_in,
                              void* d_out, int out_size, void* d_ws,
                              size_t ws_size, hipStream_t stream) {
  const float* hs  = (const float*)d_in[0];
  const int*   pos = (const int*)d_in[1];
  const float* qw  = (const float*)d_in[2];
  const float* kw  = (const float*)d_in[3];
  const float* vw  = (const float*)d_in[4];
  const float* ow  = (const float*)d_in[5];
  const float* emb = (const float*)d_in[6];
  float* out = (float*)d_out;

  char* ws = (char*)d_ws;
  const size_t MB = 1024 * 1024;
  // [0,32)   Hb  -> AO after projections consume Hb
  // [32,128) Wqkv; after gemms: [32,64) Wo, [64,96) Vt (d,s)
  // [128,160) Qb  [160,192) Kb  [192,224) Vtmp (s,d)
  bf16* Hb   = (bf16*)(ws);
  bf16* AO   = (bf16*)(ws);
  bf16* Wqkv = (bf16*)(ws + 32 * MB);
  bf16* Wo   = (bf16*)(ws + 32 * MB);
  bf16* Vt   = (bf16*)(ws + 64 * MB);
  bf16* Qb   = (bf16*)(ws + 128 * MB);
  bf16* Kb   = (bf16*)(ws + 160 * MB);
  bf16* Vtmp = (bf16*)(ws + 192 * MB);

  const int n = ED * ED;            // 16777216

  cvt4_f32_bf16<<<65536, 256, 0, stream>>>(
      hs, qw, kw, vw, Hb, Wqkv, Wqkv + (size_t)n, Wqkv + 2 * (size_t)n);

  gemm_proj<<<dim3(32, 32), 256, 0, stream>>>(Hb, Wqkv, Qb);
  gemm_proj<<<dim3(32, 32), 256, 0, stream>>>(Hb, Wqkv + (size_t)n, Kb);
  gemm_proj<<<dim3(32, 32), 256, 0, stream>>>(Hb, Wqkv + 2 * (size_t)n, Vtmp);

  // out_w conversion + V transpose (into freed Wqkv space)
  cvt_f32_bf16<<<16384, 256, 0, stream>>>(ow, Wo, n);
  transpose_v<<<dim3(32, 4, 32), 256, 0, stream>>>(Vtmp, Vt);

  rope_kernel<<<4096, 256, 0, stream>>>(Qb, Kb, pos, emb);

  attn_kernel<<<512, 256, 0, stream>>>(Qb, Kb, Vt, AO);

  gemm_out<<<dim3(32, 32), 256, 0, stream>>>(AO, Wo, out);
}

// Round 5
// 1199.605 us; speedup vs baseline: 1.0880x; 1.0880x over previous
//
#include <hip/hip_runtime.h>

// ---------------------------------------------------------------------------
// GPT-J attention on MI355X (gfx950), bf16 MFMA pipeline.
// B=2 S=2048 E=4096 H=16 D=256 ROT=64
// R5: fused gemm_qkv restored (R4 split regressed 190us);
//     attn: K/V double-buffered LDS pipeline -- one barrier/iter, prefetch
//     issued right after the barrier so the vmcnt drain at the next barrier
//     is ~free (load in flight for a full compute phase);
//     cvt kernels at 8 elems/thread.
// ---------------------------------------------------------------------------

typedef __bf16 bf16;
typedef bf16  bf16x4 __attribute__((ext_vector_type(4)));
typedef bf16  bf16x8 __attribute__((ext_vector_type(8)));
typedef float f32x4  __attribute__((ext_vector_type(4)));

#define SEQ 2048
#define ED  4096
#define NH  16
#define HD  256

__device__ __forceinline__ void async_load16(const void* g, void* l) {
  __builtin_amdgcn_global_load_lds(
      (const __attribute__((address_space(1))) void*)g,
      (__attribute__((address_space(3))) void*)l, 16, 0, 0);
}

// ---------------------------------------------------------------------------
// fused fp32 -> bf16 conversion, 4 sources, 8 elems/thread
// ---------------------------------------------------------------------------
__global__ void cvt4_f32_bf16(const float* __restrict__ s0,
                              const float* __restrict__ s1,
                              const float* __restrict__ s2,
                              const float* __restrict__ s3,
                              bf16* __restrict__ d0, bf16* __restrict__ d1,
                              bf16* __restrict__ d2, bf16* __restrict__ d3) {
  int sec = blockIdx.x >> 13;              // 8192 blocks / section
  int idx = ((blockIdx.x & 8191) * 256 + threadIdx.x) * 8;
  const float* s = sec == 0 ? s0 : sec == 1 ? s1 : sec == 2 ? s2 : s3;
  bf16* d = sec == 0 ? d0 : sec == 1 ? d1 : sec == 2 ? d2 : d3;
  float4 v0 = *(const float4*)(s + idx);
  float4 v1 = *(const float4*)(s + idx + 4);
  bf16x8 o;
  o[0] = (bf16)v0.x; o[1] = (bf16)v0.y; o[2] = (bf16)v0.z; o[3] = (bf16)v0.w;
  o[4] = (bf16)v1.x; o[5] = (bf16)v1.y; o[6] = (bf16)v1.z; o[7] = (bf16)v1.w;
  *(bf16x8*)(d + idx) = o;
}

__global__ void cvt_f32_bf16(const float* __restrict__ src,
                             bf16* __restrict__ dst, int n) {
  int idx = (blockIdx.x * 256 + threadIdx.x) * 8;
  if (idx < n) {
    float4 v0 = *(const float4*)(src + idx);
    float4 v1 = *(const float4*)(src + idx + 4);
    bf16x8 o;
    o[0] = (bf16)v0.x; o[1] = (bf16)v0.y; o[2] = (bf16)v0.z; o[3] = (bf16)v0.w;
    o[4] = (bf16)v1.x; o[5] = (bf16)v1.y; o[6] = (bf16)v1.z; o[7] = (bf16)v1.w;
    *(bf16x8*)(dst + idx) = o;
  }
}

// ---------------------------------------------------------------------------
// fused bt-GEMM: C[m,n] = dot(A[m,:], W[n,:]), W = [q_w;k_w;v_w] 12288x4096.
// 128x128 tile, 4 waves, BK=32, global_load_lds (16B), band swizzle.
// Epilogue: uniform coalesced store to (b,h,s,d) for Q, K, V(tmp).
// ---------------------------------------------------------------------------
__global__ __launch_bounds__(256) void gemm_qkv(
    const bf16* __restrict__ A, const bf16* __restrict__ W,
    bf16* __restrict__ Qb, bf16* __restrict__ Kb, bf16* __restrict__ Vtmp) {
  __shared__ bf16 As[128 * 32];
  __shared__ bf16 Bs[128 * 32];
  const int tid = threadIdx.x;
  const int w = tid >> 6, lane = tid & 63;
  const int wm = w >> 1, wn = w & 1;
  const int lo = lane & 15, hi = lane >> 4;

  // band swizzle: flat id -> (m-tile, n-tile) with 8 n per band
  const int flat = blockIdx.y * 32 + blockIdx.x;
  const int band = flat >> 8;                // 0..11
  const int xm = (flat & 255) >> 3;          // 0..31
  const int xn = (band << 3) | (flat & 7);   // 0..95
  const int tm = xm * 128;
  const int tn = xn * 128;

  const int rA0 = lane >> 2;
  const int cA0 = (lane & 3) * 8;

  const bf16* Ab = A + (size_t)tm * ED;
  const bf16* Wb = W + (size_t)tn * ED;

  f32x4 acc[4][4] = {};

  for (int k0 = 0; k0 < ED; k0 += 32) {
#pragma unroll
    for (int i = 0; i < 2; ++i) {
      int ci = w * 2 + i;
      int r = ci * 16 + rA0;
      async_load16(Ab + (size_t)r * ED + k0 + cA0, &As[ci * 512]);
      async_load16(Wb + (size_t)r * ED + k0 + cA0, &Bs[ci * 512]);
    }
    __syncthreads();
    bf16x8 af[4], bfr[4];
#pragma unroll
    for (int mt = 0; mt < 4; ++mt)
      af[mt] = *(const bf16x8*)&As[(wm * 64 + mt * 16 + lo) * 32 + hi * 8];
#pragma unroll
    for (int nt = 0; nt < 4; ++nt)
      bfr[nt] = *(const bf16x8*)&Bs[(wn * 64 + nt * 16 + lo) * 32 + hi * 8];
#pragma unroll
    for (int mt = 0; mt < 4; ++mt)
#pragma unroll
      for (int nt = 0; nt < 4; ++nt)
        acc[mt][nt] = __builtin_amdgcn_mfma_f32_16x16x32_bf16(
            af[mt], bfr[nt], acc[mt][nt], 0, 0, 0);
    __syncthreads();
  }

  const int widx = tn >> 12;     // 0=Q 1=K 2=V
  const int f0 = tn & 4095;
  bf16* Ob = widx == 0 ? Qb : (widx == 1 ? Kb : Vtmp);
#pragma unroll
  for (int mt = 0; mt < 4; ++mt) {
#pragma unroll
    for (int nt = 0; nt < 4; ++nt) {
#pragma unroll
      for (int r = 0; r < 4; ++r) {
        int m = tm + wm * 64 + mt * 16 + hi * 4 + r;
        int f = f0 + wn * 64 + nt * 16 + lo;
        int b = m >> 11, s = m & 2047;
        int h = f >> 8, d = f & 255;
        Ob[(((size_t)(b * NH + h) * SEQ) + s) * HD + d] = (bf16)acc[mt][nt][r];
      }
    }
  }
}

// ---------------------------------------------------------------------------
// V transpose: (b,h,s,d) -> (b,h,d,s). 64x64 tiles via padded LDS.
// ---------------------------------------------------------------------------
__global__ __launch_bounds__(256) void transpose_v(const bf16* __restrict__ src,
                                                   bf16* __restrict__ dst) {
  __shared__ bf16 T[64][72];
  const int bh = blockIdx.z;
  const int st = blockIdx.x;
  const int dt = blockIdx.y;
  const bf16* S = src + ((size_t)bh * SEQ + st * 64) * HD + dt * 64;
#pragma unroll
  for (int p = 0; p < 2; ++p) {
    int r = p * 32 + (threadIdx.x >> 3), c = (threadIdx.x & 7) * 8;
    *(bf16x8*)&T[r][c] = *(const bf16x8*)(S + (size_t)r * HD + c);
  }
  __syncthreads();
  bf16* D = dst + ((size_t)bh * HD + dt * 64) * SEQ + st * 64;
#pragma unroll
  for (int p = 0; p < 2; ++p) {
    int r = p * 32 + (threadIdx.x >> 3), c = (threadIdx.x & 7) * 8;
    bf16x8 v;
#pragma unroll
    for (int j = 0; j < 8; ++j) v[j] = T[c + j][r];
    *(bf16x8*)(D + (size_t)r * SEQ + c) = v;
  }
}

// ---------------------------------------------------------------------------
// out-proj GEMM, fp32 epilogue to d_out (row-major 4096x4096)
// ---------------------------------------------------------------------------
__global__ __launch_bounds__(256) void gemm_out(
    const bf16* __restrict__ A, const bf16* __restrict__ W,
    float* __restrict__ C) {
  __shared__ bf16 As[128 * 32];
  __shared__ bf16 Bs[128 * 32];
  const int tid = threadIdx.x;
  const int w = tid >> 6, lane = tid & 63;
  const int wm = w >> 1, wn = w & 1;
  const int lo = lane & 15, hi = lane >> 4;
  const int tm = blockIdx.x * 128;
  const int tn = blockIdx.y * 128;

  const int rA0 = lane >> 2;
  const int cA0 = (lane & 3) * 8;

  const bf16* Ab = A + (size_t)tm * ED;
  const bf16* Wb = W + (size_t)tn * ED;

  f32x4 acc[4][4] = {};

  for (int k0 = 0; k0 < ED; k0 += 32) {
#pragma unroll
    for (int i = 0; i < 2; ++i) {
      int ci = w * 2 + i;
      int r = ci * 16 + rA0;
      async_load16(Ab + (size_t)r * ED + k0 + cA0, &As[ci * 512]);
      async_load16(Wb + (size_t)r * ED + k0 + cA0, &Bs[ci * 512]);
    }
    __syncthreads();
    bf16x8 af[4], bfr[4];
#pragma unroll
    for (int mt = 0; mt < 4; ++mt)
      af[mt] = *(const bf16x8*)&As[(wm * 64 + mt * 16 + lo) * 32 + hi * 8];
#pragma unroll
    for (int nt = 0; nt < 4; ++nt)
      bfr[nt] = *(const bf16x8*)&Bs[(wn * 64 + nt * 16 + lo) * 32 + hi * 8];
#pragma unroll
    for (int mt = 0; mt < 4; ++mt)
#pragma unroll
      for (int nt = 0; nt < 4; ++nt)
        acc[mt][nt] = __builtin_amdgcn_mfma_f32_16x16x32_bf16(
            af[mt], bfr[nt], acc[mt][nt], 0, 0, 0);
    __syncthreads();
  }

#pragma unroll
  for (int mt = 0; mt < 4; ++mt)
#pragma unroll
    for (int nt = 0; nt < 4; ++nt)
#pragma unroll
      for (int r = 0; r < 4; ++r) {
        int m = tm + wm * 64 + mt * 16 + hi * 4 + r;
        int n = tn + wn * 64 + nt * 16 + lo;
        C[(size_t)m * ED + n] = acc[mt][nt][r];
      }
}

// ---------------------------------------------------------------------------
// RoPE, vectorized: one thread = 4 interleaved pairs (bf16x8, 16 B).
// ---------------------------------------------------------------------------
__global__ void rope_kernel(bf16* __restrict__ Qb, bf16* __restrict__ Kb,
                            const int* __restrict__ pos_ids,
                            const float* __restrict__ emb) {
  int idx = blockIdx.x * 256 + threadIdx.x;
  int g = idx & 7;
  int s = (idx >> 3) & 2047;
  int h = (idx >> 14) & 15;
  int b = (idx >> 18) & 1;
  int t = idx >> 19;
  bf16* T = t ? Kb : Qb;
  int pos = pos_ids[b * SEQ + s];
  const float* e = emb + pos * 64;
  size_t base = (((size_t)(b * NH + h) * SEQ) + s) * HD + g * 8;
  bf16x8 v = *(bf16x8*)(T + base);
  bf16x8 o;
#pragma unroll
  for (int j = 0; j < 4; ++j) {
    int p = g * 4 + j;
    float sn = e[p], cs = e[32 + p];
    float x0 = (float)v[2 * j], x1 = (float)v[2 * j + 1];
    o[2 * j]     = (bf16)(x0 * cs - x1 * sn);
    o[2 * j + 1] = (bf16)(x1 * cs + x0 * sn);
  }
  *(bf16x8*)(T + base) = o;
}

// ---------------------------------------------------------------------------
// stage one 64-col K tile + V tile into the given LDS buffers (swizzled).
// ---------------------------------------------------------------------------
__device__ __forceinline__ void stage_kv(const bf16* __restrict__ Kh,
                                         const bf16* __restrict__ Vh,
                                         bf16* KsBuf, bf16* VsBuf,
                                         int kt, int w, int lane) {
#pragma unroll
  for (int i = 0; i < 8; ++i) {
    int ci = w * 8 + i;
    int r = ci * 2 + (lane >> 5);
    int cc = (lane & 31) ^ (r & 7);
    async_load16(Kh + ((size_t)(kt * 64 + r)) * HD + cc * 8, KsBuf + ci * 512);
  }
#pragma unroll
  for (int i = 0; i < 8; ++i) {
    int ci = w * 8 + i;
    int d = ci * 8 + (lane >> 3);
    int cc = (lane & 7) ^ (d & 7);
    async_load16(Vh + (size_t)d * SEQ + kt * 64 + cc * 8, VsBuf + ci * 512);
  }
}

// ---------------------------------------------------------------------------
// Flash attention (causal), qt-paired, XCD-local grid, double-buffered LDS.
// Grid: 512 1-D; flat = slot*32 + bh => flat%8 == bh%8 (XCD-local K/V in L2).
// Per iteration: ONE barrier; prefetch of tile kt+1 issued right after it
// into the other buffer, so the next barrier's vmcnt drain waits on loads
// that have been in flight for a whole compute phase.
// LDS: Ks 2x32K + Vs 2x32K + Ps 8K = 136 KB -> 1 block/CU.
// XOR swizzle (phys chunk = logical chunk ^ (row&7)) on all tiles.
// ---------------------------------------------------------------------------
__global__ __launch_bounds__(256) void attn_kernel(
    const bf16* __restrict__ Qb, const bf16* __restrict__ Kb,
    const bf16* __restrict__ Vt, bf16* __restrict__ AO) {
  __shared__ bf16 Ks[2][64 * 256];   // 64 KB
  __shared__ bf16 Vs[2][256 * 64];   // 64 KB
  __shared__ bf16 Ps[4 * 16 * 64];   // 8 KB, wave-private strips
  const int tid = threadIdx.x;
  const int w = tid >> 6, lane = tid & 63;
  const int lo = lane & 15, hi = lane >> 4;
  const int slot = blockIdx.x >> 5;   // 0..15
  const int bh = blockIdx.x & 31;     // 0..31

  const bf16* Qh = Qb + (size_t)bh * SEQ * HD;
  const bf16* Kh = Kb + (size_t)bh * SEQ * HD;
  const bf16* Vh = Vt + (size_t)bh * HD * SEQ;
  const int b = bh >> 4, h = bh & 15;

  for (int half = 0; half < 2; ++half) {
    const int qt = half ? (31 - slot) : slot;

    // prefetch tile 0 into buffer 0
    stage_kv(Kh, Vh, &Ks[0][0], &Vs[0][0], 0, w, lane);

    bf16x8 aq[8];
    const int qrow = qt * 64 + w * 16 + lo;
#pragma unroll
    for (int ks = 0; ks < 8; ++ks)
      aq[ks] = *(const bf16x8*)(Qh + (size_t)qrow * HD + ks * 32 + hi * 8);

    f32x4 o[16] = {};
    float mrow[4], lrow[4];
#pragma unroll
    for (int r = 0; r < 4; ++r) { mrow[r] = -3e38f; lrow[r] = 0.f; }

    for (int kt = 0; kt <= qt; ++kt) {
      const int cur = kt & 1;
      __syncthreads();   // tile kt resident; prev tile's readers all done
      if (kt < qt)
        stage_kv(Kh, Vh, &Ks[cur ^ 1][0], &Vs[cur ^ 1][0], kt + 1, w, lane);
      const bf16* Kc = &Ks[cur][0];
      const bf16* Vc = &Vs[cur][0];

      // S strip: 16 rows x 64 cols
      float sv[4][4];
#pragma unroll
      for (int nt = 0; nt < 4; ++nt) {
        f32x4 sacc = {};
#pragma unroll
        for (int ks = 0; ks < 8; ++ks) {
          int row = nt * 16 + lo;
          bf16x8 bk = *(const bf16x8*)
              &Kc[row * HD + ((((ks << 2) + hi) ^ (row & 7)) << 3)];
          sacc = __builtin_amdgcn_mfma_f32_16x16x32_bf16(aq[ks], bk, sacc, 0, 0, 0);
        }
#pragma unroll
        for (int r = 0; r < 4; ++r) {
          float x = sacc[r] * 0.0625f;
          if (kt == qt) {
            int col = kt * 64 + nt * 16 + lo;
            int row = qt * 64 + w * 16 + hi * 4 + r;
            if (col > row) x = -1e30f;
          }
          sv[nt][r] = x;
        }
      }

      // online softmax (row lives in 16 lanes sharing hi)
      float alpha[4];
#pragma unroll
      for (int r = 0; r < 4; ++r) {
        float mx = fmaxf(fmaxf(sv[0][r], sv[1][r]), fmaxf(sv[2][r], sv[3][r]));
        mx = fmaxf(mx, __shfl_xor(mx, 1));
        mx = fmaxf(mx, __shfl_xor(mx, 2));
        mx = fmaxf(mx, __shfl_xor(mx, 4));
        mx = fmaxf(mx, __shfl_xor(mx, 8));
        float mnew = fmaxf(mrow[r], mx);
        alpha[r] = __expf(mrow[r] - mnew);
        mrow[r] = mnew;
        float sum = 0.f;
#pragma unroll
        for (int nt = 0; nt < 4; ++nt) {
          float p = __expf(sv[nt][r] - mnew);
          sv[nt][r] = p;
          sum += p;
        }
        sum += __shfl_xor(sum, 1);
        sum += __shfl_xor(sum, 2);
        sum += __shfl_xor(sum, 4);
        sum += __shfl_xor(sum, 8);
        lrow[r] = lrow[r] * alpha[r] + sum;
      }

#pragma unroll
      for (int nt2 = 0; nt2 < 16; ++nt2)
#pragma unroll
        for (int r = 0; r < 4; ++r) o[nt2][r] *= alpha[r];

      // P: C-layout -> wave-private swizzled LDS strip -> A-layout
#pragma unroll
      for (int nt = 0; nt < 4; ++nt)
#pragma unroll
        for (int r = 0; r < 4; ++r) {
          int prow = hi * 4 + r;
          int chunk = nt * 2 + (lo >> 3);
          Ps[w * 1024 + prow * 64 + (((chunk ^ (prow & 7)) << 3) | (lo & 7))] =
              (bf16)sv[nt][r];
        }
      bf16x8 pa[2];
#pragma unroll
      for (int k2 = 0; k2 < 2; ++k2)
        pa[k2] = *(const bf16x8*)
            &Ps[w * 1024 + lo * 64 + ((((k2 << 2) + hi) ^ (lo & 7)) << 3)];

      // O += P @ V  (16x64 @ 64x256)
#pragma unroll
      for (int nt2 = 0; nt2 < 16; ++nt2) {
#pragma unroll
        for (int k2 = 0; k2 < 2; ++k2) {
          int row = nt2 * 16 + lo;
          bf16x8 bv = *(const bf16x8*)
              &Vc[row * 64 + ((((k2 << 2) + hi) ^ (row & 7)) << 3)];
          o[nt2] = __builtin_amdgcn_mfma_f32_16x16x32_bf16(pa[k2], bv, o[nt2], 0, 0, 0);
        }
      }
    }
    __syncthreads();  // last tile's readers done before next half re-stages buf0

    // epilogue: normalize, write AO as (b, s, h*256+d) bf16
#pragma unroll
    for (int r = 0; r < 4; ++r) {
      float inv = 1.f / lrow[r];
      int srow = qt * 64 + w * 16 + hi * 4 + r;
      size_t base = ((size_t)(b * SEQ + srow)) * ED + h * HD;
#pragma unroll
      for (int nt2 = 0; nt2 < 16; ++nt2)
        AO[base + nt2 * 16 + lo] = (bf16)(o[nt2][r] * inv);
    }
  }
}

// ---------------------------------------------------------------------------
// launch
// ---------------------------------------------------------------------------
extern "C" void kernel_launch(void* const* d_in, const int* in_sizes, int n_in,
                              void* d_out, int out_size, void* d_ws,
                              size_t ws_size, hipStream_t stream) {
  const float* hs  = (const float*)d_in[0];
  const int*   pos = (const int*)d_in[1];
  const float* qw  = (const float*)d_in[2];
  const float* kw  = (const float*)d_in[3];
  const float* vw  = (const float*)d_in[4];
  const float* ow  = (const float*)d_in[5];
  const float* emb = (const float*)d_in[6];
  float* out = (float*)d_out;

  char* ws = (char*)d_ws;
  const size_t MB = 1024 * 1024;
  // [0,32)   Hb  -> AO after gemm_qkv consumes Hb
  // [32,128) Wqkv; after gemm_qkv: [32,64) Wo, [64,96) Vt (d,s)
  // [128,160) Qb  [160,192) Kb  [192,224) Vtmp (s,d)
  bf16* Hb   = (bf16*)(ws);
  bf16* AO   = (bf16*)(ws);
  bf16* Wqkv = (bf16*)(ws + 32 * MB);
  bf16* Wo   = (bf16*)(ws + 32 * MB);
  bf16* Vt   = (bf16*)(ws + 64 * MB);
  bf16* Qb   = (bf16*)(ws + 128 * MB);
  bf16* Kb   = (bf16*)(ws + 160 * MB);
  bf16* Vtmp = (bf16*)(ws + 192 * MB);

  const int n = ED * ED;            // 16777216

  cvt4_f32_bf16<<<32768, 256, 0, stream>>>(
      hs, qw, kw, vw, Hb, Wqkv, Wqkv + (size_t)n, Wqkv + 2 * (size_t)n);

  gemm_qkv<<<dim3(32, 96), 256, 0, stream>>>(Hb, Wqkv, Qb, Kb, Vtmp);

  // out_w conversion + V transpose (into freed Wqkv space)
  cvt_f32_bf16<<<8192, 256, 0, stream>>>(ow, Wo, n);
  transpose_v<<<dim3(32, 4, 32), 256, 0, stream>>>(Vtmp, Vt);

  rope_kernel<<<4096, 256, 0, stream>>>(Qb, Kb, pos, emb);

  attn_kernel<<<512, 256, 0, stream>>>(Qb, Kb, Vt, AO);

  gemm_out<<<dim3(32, 32), 256, 0, stream>>>(AO, Wo, out);
}